// Round 23
// baseline (63.003 us; speedup 1.0000x reference)
//
#include <hip/hip_runtime.h>

// sPLL — R17 structure (best: 54.8 µs) + ONLY the xnz wave-uniform branch
// (isolated A/B; R21 confounded it with nontemporal stores):
//   * 512 blocks, 2 parity roles; both compute all 500 steps from the same
//     init (bitwise-identical); role r stores timesteps with t%2==r.
//   * FPBARs retained (R22 showed removing them costs ~2 µs).
//   * xnz: x is block-uniform {0,1}, P(1)=0.1 => scalar-skip the 4-op pulse
//     path on ~90% of steps. Bit-exact (verified in R16/R19 passes):
//     w0 + 0.0f == w0 since w0 >= +0.
static constexpr int T  = 500;
static constexpr int BS = 256;
static constexpr int N  = 256;
static constexpr int U  = 10;

#define FPBAR(x) asm("" : "+v"(x))

struct Cell { float Vl, Il, crl, Vt, itrg, ifac, crt; bool sp; };

__device__ __forceinline__ void do_step(float x, unsigned xu, float steady,
                                        Cell& c, float& sl_out, float& st_out)
{
    const float RC = 999.99993896484375f;   // f32(1/f32(0.001))
    // ---- LIF ----
    float u0 = c.Il * 0.8f;                      FPBAR(u0);
    float u1 = c.sp ? 1e-3f : 0.0f;                         // == 1e-3f*spk
    c.Il = u0 + u1;                              FPBAR(c.Il);
    float u3 = -c.Vl * 100.0f;                   FPBAR(u3);
    float u4 = c.Il + steady;                    FPBAR(u4);
    float u6 = __builtin_fmaf(u4, RC, u3);       FPBAR(u6);
    c.Vl = __builtin_fmaf(1e-3f, u6, c.Vl);      FPBAR(c.Vl);
    bool  bl  = c.Vl > 1.0f;
    float crm = c.crl - 1.0f;                               // exact small ints
    bool  rg  = crm <= 0.0f;
    c.crl = bl ? 2.0f : crm;                                // == 2*spk+ns*(crl-1)
    c.Vl  = (!bl && rg) ? c.Vl : 0.0f;                      // verified exact
    sl_out = bl ? 1.0f : 0.0f;
    // ---- TDE ----
    float u13 = bl ? 1.0f : c.ifac;                         // == spk + ifac*ns
    c.ifac = u13 * 0.8f;                         FPBAR(c.ifac);
    float w0 = c.itrg * 0.9f;                    FPBAR(w0);
    if (xu != 0u) {                              // x == 1.0f exactly (uniform)
        float df    = c.ifac + c.ifac;                      // exact 2x
        bool  m1    = c.ifac > 0.1f;
        float pulse = m1 ? df : 0.0f;                       // == (x*2)*ifac*m1
        float itn   = w0 + pulse;                FPBAR(itn);
        c.itrg = itn;
    } else {
        c.itrg = w0;                             // w0 + +0 == w0 (verified)
    }
    float u18 = -c.Vt * 100.0f;                  FPBAR(u18);
    float u20 = __builtin_fmaf(c.itrg, RC, u18); FPBAR(u20);
    c.Vt = __builtin_fmaf(1e-3f, u20, c.Vt);     FPBAR(c.Vt);
    bool  bt  = c.Vt > 1.0f;
    float ctm = c.crt - 1.0f;
    bool  rg2 = ctm <= 0.0f;
    c.crt = bt ? 2.0f : ctm;
    c.Vt  = (!bt && rg2) ? c.Vt : 0.0f;
    st_out = bt ? 1.0f : 0.0f;
    c.sp = bt;
}

template <int PAR>
__device__ __forceinline__ void run_group(const float* sxp, float steady, Cell& c,
                                          float*& p0, float*& p1)
{
    const size_t step = (size_t)BS * N;
    const float2 x01 = *reinterpret_cast<const float2*>(sxp + 0);
    const float2 x23 = *reinterpret_cast<const float2*>(sxp + 2);
    const float2 x45 = *reinterpret_cast<const float2*>(sxp + 4);
    const float2 x67 = *reinterpret_cast<const float2*>(sxp + 6);
    const float2 x89 = *reinterpret_cast<const float2*>(sxp + 8);
    const float xs[U] = {x01.x, x01.y, x23.x, x23.y, x45.x,
                         x45.y, x67.x, x67.y, x89.x, x89.y};
    float sl, st;
#pragma unroll
    for (int j = 0; j < U; ++j) {
        unsigned xu = __builtin_amdgcn_readfirstlane(__float_as_uint(xs[j]));
        do_step(xs[j], xu, steady, c, sl, st);
        if ((j & 1) == PAR) {                 // t = g*10+j, parity == j&1
            p0[(size_t)j * step] = sl;
            p1[(size_t)j * step] = st;
        }
    }
    p0 += (size_t)U * step;
    p1 += (size_t)U * step;
}

__global__ __launch_bounds__(256, 2) void spll_kernel(
    const float* __restrict__ inp,      // (T, BS)
    const float* __restrict__ current,  // (N,)
    float* __restrict__ out)            // (2, T, BS, N)
{
#pragma clang fp contract(off)
    const int b    = blockIdx.x & (BS - 1);
    const int role = blockIdx.x >> 8;        // 0 stores even t, 1 stores odd t
    const int n    = threadIdx.x;

    __shared__ __align__(16) float s_inp[T];
    for (int i = threadIdx.x; i < T; i += blockDim.x)
        s_inp[i] = inp[i * BS + b];
    __syncthreads();

    const float steady = current[n];
    Cell c = {1.0f, 0.0f, 0.0f, 0.0f, 0.0f, 0.0f, 0.0f, false};

    float* p0 = out + (size_t)b * N + n;
    float* p1 = p0 + (size_t)T * BS * N;

    if (role == 0) {
        for (int g = 0; g < T / U; ++g)
            run_group<0>(&s_inp[g * U], steady, c, p0, p1);
    } else {
        for (int g = 0; g < T / U; ++g)
            run_group<1>(&s_inp[g * U], steady, c, p0, p1);
    }
}

extern "C" void kernel_launch(void* const* d_in, const int* in_sizes, int n_in,
                              void* d_out, int out_size, void* d_ws, size_t ws_size,
                              hipStream_t stream) {
    const float* a0 = (const float*)d_in[0];
    const float* a1 = (const float*)d_in[1];
    const float* inp = a0;
    const float* cur = a1;
    if (n_in >= 2 && in_sizes[0] == N && in_sizes[1] == T * BS) { inp = a1; cur = a0; }
    float* out = (float*)d_out;
    spll_kernel<<<dim3(2 * BS), dim3(N), 0, stream>>>(inp, cur, out);
}

// Round 24
// 54.709 us; speedup vs baseline: 1.1516x; 1.1516x over previous
//
#include <hip/hip_runtime.h>

// sPLL — FINAL: R17 verbatim (best of 12 measured variants: 54.8 µs).
//   * Arithmetic identified by R8-R10 bisection, bit-exact vs the np ref
//     on all 65.5M outputs (absmax 0.0 in R11-R23):
//     recip-mul (*100.0f, *999.99993896484375f), second-operand-FMA drive,
//     FMA V-accumulate, unfused Il/itrg leak updates, exact select algebra.
//   * Structure: 512 blocks, 2 parity roles; both roles compute all 500
//     steps from the same init (bitwise-identical trajectories); role r
//     stores timesteps with t%2==r. 2 waves/SIMD = measured optimum of the
//     redundancy family (R=1: 61.7, R=2: 54.8, R=3: 70.5 µs).
//   * 54.8 µs = 1.50x the calibrated 36.5 µs HBM write floor; residue is
//     serial-recurrence latency at problem-fixed 65536-way parallelism.
static constexpr int T  = 500;
static constexpr int BS = 256;
static constexpr int N  = 256;
static constexpr int U  = 10;

#define FPBAR(x) asm("" : "+v"(x))

struct Cell { float Vl, Il, crl, Vt, itrg, ifac, crt; bool sp; };

__device__ __forceinline__ void do_step(float x, float steady, Cell& c,
                                        float& sl_out, float& st_out)
{
    const float RC = 999.99993896484375f;   // f32(1/f32(0.001))
    // ---- LIF ----
    float u0 = c.Il * 0.8f;                      FPBAR(u0);
    float u1 = c.sp ? 1e-3f : 0.0f;                         // == 1e-3f*spk
    c.Il = u0 + u1;                              FPBAR(c.Il);
    float u3 = -c.Vl * 100.0f;                   FPBAR(u3);
    float u4 = c.Il + steady;                    FPBAR(u4);
    float u6 = __builtin_fmaf(u4, RC, u3);       FPBAR(u6);
    c.Vl = __builtin_fmaf(1e-3f, u6, c.Vl);      FPBAR(c.Vl);
    bool  bl  = c.Vl > 1.0f;                                // == (Vl-1>0)
    float crm = c.crl - 1.0f;                               // exact small ints
    bool  rg  = crm <= 0.0f;
    c.crl = bl ? 2.0f : crm;                                // == 2*spk+ns*(crl-1)
    c.Vl  = (!bl && rg) ? c.Vl : 0.0f;                      // verified exact
    sl_out = bl ? 1.0f : 0.0f;
    // ---- TDE ----
    float u13 = bl ? 1.0f : c.ifac;                         // == spk + ifac*ns
    c.ifac = u13 * 0.8f;                         FPBAR(c.ifac);
    float w0 = c.itrg * 0.9f;                    FPBAR(w0);
    float df  = c.ifac + c.ifac;                            // exact 2x
    float dfx = x * df;                          FPBAR(dfx);// exact (x in {0,1})
    bool  m1  = c.ifac > 0.1f;
    float pulse = m1 ? dfx : 0.0f;                          // == (x*2)*ifac*m1
    c.itrg = w0 + pulse;                         FPBAR(c.itrg);
    float u18 = -c.Vt * 100.0f;                  FPBAR(u18);
    float u20 = __builtin_fmaf(c.itrg, RC, u18); FPBAR(u20);
    c.Vt = __builtin_fmaf(1e-3f, u20, c.Vt);     FPBAR(c.Vt);
    bool  bt  = c.Vt > 1.0f;
    float ctm = c.crt - 1.0f;
    bool  rg2 = ctm <= 0.0f;
    c.crt = bt ? 2.0f : ctm;
    c.Vt  = (!bt && rg2) ? c.Vt : 0.0f;
    st_out = bt ? 1.0f : 0.0f;
    c.sp = bt;
}

template <int PAR>
__device__ __forceinline__ void run_group(const float* sxp, float steady, Cell& c,
                                          float*& p0, float*& p1)
{
    const size_t step = (size_t)BS * N;
    const float2 x01 = *reinterpret_cast<const float2*>(sxp + 0);
    const float2 x23 = *reinterpret_cast<const float2*>(sxp + 2);
    const float2 x45 = *reinterpret_cast<const float2*>(sxp + 4);
    const float2 x67 = *reinterpret_cast<const float2*>(sxp + 6);
    const float2 x89 = *reinterpret_cast<const float2*>(sxp + 8);
    const float xs[U] = {x01.x, x01.y, x23.x, x23.y, x45.x,
                         x45.y, x67.x, x67.y, x89.x, x89.y};
    float sl, st;
#pragma unroll
    for (int j = 0; j < U; ++j) {
        do_step(xs[j], steady, c, sl, st);
        if ((j & 1) == PAR) {                 // t = g*10+j, parity == j&1
            p0[(size_t)j * step] = sl;
            p1[(size_t)j * step] = st;
        }
    }
    p0 += (size_t)U * step;
    p1 += (size_t)U * step;
}

__global__ __launch_bounds__(256, 2) void spll_kernel(
    const float* __restrict__ inp,      // (T, BS)
    const float* __restrict__ current,  // (N,)
    float* __restrict__ out)            // (2, T, BS, N)
{
#pragma clang fp contract(off)
    const int b    = blockIdx.x & (BS - 1);
    const int role = blockIdx.x >> 8;        // 0 stores even t, 1 stores odd t
    const int n    = threadIdx.x;

    __shared__ __align__(16) float s_inp[T];
    for (int i = threadIdx.x; i < T; i += blockDim.x)
        s_inp[i] = inp[i * BS + b];
    __syncthreads();

    const float steady = current[n];
    Cell c = {1.0f, 0.0f, 0.0f, 0.0f, 0.0f, 0.0f, 0.0f, false};

    float* p0 = out + (size_t)b * N + n;
    float* p1 = p0 + (size_t)T * BS * N;

    if (role == 0) {
        for (int g = 0; g < T / U; ++g)
            run_group<0>(&s_inp[g * U], steady, c, p0, p1);
    } else {
        for (int g = 0; g < T / U; ++g)
            run_group<1>(&s_inp[g * U], steady, c, p0, p1);
    }
}

extern "C" void kernel_launch(void* const* d_in, const int* in_sizes, int n_in,
                              void* d_out, int out_size, void* d_ws, size_t ws_size,
                              hipStream_t stream) {
    const float* a0 = (const float*)d_in[0];
    const float* a1 = (const float*)d_in[1];
    const float* inp = a0;
    const float* cur = a1;
    if (n_in >= 2 && in_sizes[0] == N && in_sizes[1] == T * BS) { inp = a1; cur = a0; }
    float* out = (float*)d_out;
    spll_kernel<<<dim3(2 * BS), dim3(N), 0, stream>>>(inp, cur, out);
}